// Round 5
// baseline (219.244 us; speedup 1.0000x reference)
//
#include <hip/hip_runtime.h>

#define NSAMP 131072
#define DIMS 8
#define NPCE 495
#define KP 512          // K padded to 512
#define NOUT 256
#define BM 64           // samples per block
#define SK 32           // K per substage
#define NSTG (KP / SK)  // 16 substages
#define NCH 4           // K-chunks (128 K each = 4 substages)
#define NH 70           // half-products per 4-dim half (order<=4)
#define HS 68           // At/Bt sample stride: 136B, words==2 mod 32 -> banks spread by h
#define PS 40           // Psi row stride: 80B rows -> 16B-aligned b128 reads, uniform banks

typedef _Float16 half8 __attribute__((ext_vector_type(8)));
typedef _Float16 h16x2 __attribute__((ext_vector_type(2)));
typedef float f32x4 __attribute__((ext_vector_type(4)));

__device__ __forceinline__ unsigned short f2h(float f) {
    return __builtin_bit_cast(unsigned short, (_Float16)f);  // v_cvt_f16_f32, RTNE
}

// packed f16 multiply of two sample-pairs: one v_pk_mul_f16
__device__ __forceinline__ unsigned pkmul(unsigned a, unsigned b) {
    h16x2 r = __builtin_bit_cast(h16x2, a) * __builtin_bit_cast(h16x2, b);
    return __builtin_bit_cast(unsigned, r);
}

// Rank of 4-dim multi-index (sum<=4) in the canonical nest enumeration.
__device__ int rank4(int a0, int a1, int a2, int a3) {
    int idx = 0;
    for (int b0 = 0; b0 <= 4; ++b0)
        for (int b1 = 0; b1 <= 4 - b0; ++b1)
            for (int b2 = 0; b2 <= 4 - b0 - b1; ++b2)
                for (int b3 = 0; b3 <= 4 - b0 - b1 - b2; ++b3) {
                    if (b0 == a0 && b1 == a1 && b2 == a2 && b3 == a3) return idx;
                    ++idx;
                }
    return 0;
}

__device__ __forceinline__ int code_of(const int* mi, int k) {
    if (k >= NPCE) return 0;  // h1=h2=0 -> psi=1, weight row is zeroed
    const int* m = &mi[k * DIMS];
    int h1 = rank4(m[0], m[1], m[2], m[3]);
    int h2 = rank4(m[4], m[5], m[6], m[7]);
    return h1 | (h2 << 8);
}

// prep: weight -> f16 [256][512] with PERMUTED rows (epilogue dwordx4 stores):
// row n holds original column o = (n&~63) | ((n&15)<<2) | ((n>>4)&3).
// codes -> dword layout hcode2[kg][stage] = code(k0) | code(k0+1)<<16,
// k0 = stage*SK + kg*2  (per-thread-contiguous, uint4 per chunk in pce).
__global__ __launch_bounds__(256) void prep_kernel(const float* __restrict__ w,
                                                   const int* __restrict__ mi,
                                                   unsigned short* __restrict__ wb,
                                                   unsigned* __restrict__ hcode2) {
    int t = blockIdx.x * 256 + threadIdx.x;
    if (t < NOUT * KP) {
        int n = t >> 9;
        int k = t & (KP - 1);
        int o = (n & ~63) | ((n & 15) << 2) | ((n >> 4) & 3);
        float v = (k < NPCE) ? w[o * NPCE + k] : 0.0f;
        wb[t] = f2h(v);
    }
    if (t < 16 * NSTG) {
        int kg = t >> 4;        // 0..15
        int s = t & (NSTG - 1); // 0..15
        int k0 = s * SK + kg * 2;
        unsigned c0 = (unsigned)code_of(mi, k0);
        unsigned c1 = (unsigned)code_of(mi, k0 + 1);
        hcode2[kg * NSTG + s] = c0 | (c1 << 16);
    }
}

// Build 35 of the 70 half-products (compile-time range -> full DCE/CSE).
template <int LO, int HI>
__device__ __forceinline__ void build_half(const float H0[5], const float H1[5],
                                           const float H2[5], const float H3[5],
                                           unsigned short* dst, int s) {
    int idx = 0;
    #pragma unroll
    for (int a0 = 0; a0 <= 4; ++a0)
        #pragma unroll
        for (int a1 = 0; a1 <= 4 - a0; ++a1)
            #pragma unroll
            for (int a2 = 0; a2 <= 4 - a0 - a1; ++a2)
                #pragma unroll
                for (int a3 = 0; a3 <= 4 - a0 - a1 - a2; ++a3) {
                    if (idx >= LO && idx < HI) {
                        float p = H0[a0] * H1[a1] * H2[a2] * H3[a3];
                        dst[idx * HS + s] = f2h(p);
                    }
                    ++idx;
                }
}

__device__ __forceinline__ void hermite5(float x, float H[5]) {
    const float rn2 = 0.70710678118654752f;
    const float rn3 = 0.40824829046386302f;
    const float rn4 = 0.20412414523193151f;
    float r1 = x;
    float r2 = x * r1 - 1.0f;
    float r3 = x * r2 - 2.0f * r1;
    float r4 = x * r3 - 3.0f * r2;
    H[0] = 1.0f; H[1] = r1; H[2] = r2 * rn2; H[3] = r3 * rn3; H[4] = r4 * rn4;
}

__global__ __launch_bounds__(256, 4) void pce_kernel(const float* __restrict__ x,
                                                     const unsigned short* __restrict__ wb,
                                                     const unsigned* __restrict__ hcode2,
                                                     float* __restrict__ out) {
    __shared__ __attribute__((aligned(16))) unsigned short At[NH * HS];       // 9.52 KB
    __shared__ __attribute__((aligned(16))) unsigned short Bt[NH * HS];       // 9.52 KB
    __shared__ __attribute__((aligned(16))) unsigned short Psi[NCH][BM * PS]; // 20.48 KB
    // total 39.5 KB -> 4 blocks/CU

    const int tid = threadIdx.x;
    const int lane = tid & 63;
    const int wave = tid >> 6;
    const int quad = lane >> 4;
    const int l15 = lane & 15;
    const int m0 = blockIdx.x * BM;

    // Gather mapping: thread owns 2 k (pair kg) x 4 samples (s0..s0+3).
    const int kg = tid & 15;
    const int s0 = (tid >> 4) * 4;
    const unsigned* hcp = &hcode2[kg * NSTG];

    // ---- issue early prefetches (hidden under the builder) ----
    uint4 cdc = *(const uint4*)&hcp[0];   // chunk-0 codes (4 substages)

    // 2-deep W prefetch: bn[parity] holds substage s columns, 2 substages of
    // latency cover for the L2 reads (one substage was marginal vs ~300cy).
    half8 bn[2][4];
    auto loadB = [&](int s, half8* dst) {
        #pragma unroll
        for (int in = 0; in < 4; ++in) {
            int n = wave * 64 + in * 16 + l15;
            dst[in] = *(const half8*)&wb[n * KP + s * SK + quad * 8];
        }
    };
    loadB(0, bn[0]);
    loadB(1, bn[1]);

    // ---- Builder: wave -> (half = wave>>1, term range = wave&1), lane = sample.
    {
        const int half = wave >> 1;
        const float4 xv = *(const float4*)&x[(m0 + lane) * DIMS + half * 4];
        float H0[5], H1[5], H2[5], H3[5];
        hermite5(xv.x, H0);
        hermite5(xv.y, H1);
        hermite5(xv.z, H2);
        hermite5(xv.w, H3);
        unsigned short* dst = half ? Bt : At;
        if (wave & 1) build_half<35, 70>(H0, H1, H2, H3, dst, lane);
        else          build_half<0, 35>(H0, H1, H2, H3, dst, lane);
    }

    f32x4 acc[4][4] = {};

    // Produce one 32-wide substage into Psi[buf]:
    // 4 ds_read_b64 + 4 v_pk_mul_f16 + 4 v_perm_b32 + 4 ds_write_b32.
    auto gather = [&](unsigned c, int buf) {
        int h1a = c & 255, h2a = (c >> 8) & 255;   // even k
        int h1b = (c >> 16) & 255, h2b = c >> 24;  // odd k
        uint2 av0 = *(const uint2*)&At[h1a * HS + s0];
        uint2 bv0 = *(const uint2*)&Bt[h2a * HS + s0];
        uint2 av1 = *(const uint2*)&At[h1b * HS + s0];
        uint2 bv1 = *(const uint2*)&Bt[h2b * HS + s0];
        unsigned p0l = pkmul(av0.x, bv0.x), p0h = pkmul(av0.y, bv0.y);
        unsigned p1l = pkmul(av1.x, bv1.x), p1h = pkmul(av1.y, bv1.y);
        unsigned short* base = &Psi[buf][kg * 2];
        *(unsigned*)&base[(s0 + 0) * PS] = __builtin_amdgcn_perm(p1l, p0l, 0x05040100u);
        *(unsigned*)&base[(s0 + 1) * PS] = __builtin_amdgcn_perm(p1l, p0l, 0x07060302u);
        *(unsigned*)&base[(s0 + 2) * PS] = __builtin_amdgcn_perm(p1h, p0h, 0x05040100u);
        *(unsigned*)&base[(s0 + 3) * PS] = __builtin_amdgcn_perm(p1h, p0h, 0x07060302u);
    };

    __syncthreads();   // At/Bt ready

    uint4 cdn = cdc;
    for (int c = 0; c < NCH; ++c) {
        // ---- produce phase: 4 substages, no intervening syncs ----
        if (c > 0) __syncthreads();   // consume of chunk c-1 fully drained
        gather(cdc.x, 0);
        gather(cdc.y, 1);
        gather(cdc.z, 2);
        gather(cdc.w, 3);
        __syncthreads();              // Psi chunk visible
        if (c + 1 < NCH) cdn = *(const uint4*)&hcp[(c + 1) * 4];

        // ---- consume phase: 4 substages x 16 MFMA, barrier-free stream ----
        #pragma unroll
        for (int t = 0; t < 4; ++t) {
            const int s = c * 4 + t;
            half8 bc[4];
            #pragma unroll
            for (int in = 0; in < 4; ++in) bc[in] = bn[s & 1][in];  // capture (vmcnt)
            if (s + 2 < NSTG) loadB(s + 2, bn[s & 1]);              // refill slot
            half8 af[4];
            #pragma unroll
            for (int im = 0; im < 4; ++im)
                af[im] = *(const half8*)&Psi[t][(im * 16 + l15) * PS + quad * 8];
            #pragma unroll
            for (int im = 0; im < 4; ++im)
                #pragma unroll
                for (int in = 0; in < 4; ++in)
                    acc[im][in] = __builtin_amdgcn_mfma_f32_16x16x32_f16(
                        af[im], bc[in], acc[im][in], 0, 0, 0);
        }
        cdc = cdn;
    }

    // ---- epilogue: permuted weights make lane's 4 'in' values 4 consecutive
    // output columns -> coalesced dwordx4 nontemporal stores (never re-read;
    // skip L2 write-allocate pressure on the shared write path).
    // NOTE: __builtin_nontemporal_store needs a clang ext_vector type (f32x4),
    // not HIP's float4 class.
    #pragma unroll
    for (int im = 0; im < 4; ++im) {
        #pragma unroll
        for (int i = 0; i < 4; ++i) {
            int m = m0 + im * 16 + quad * 4 + i;
            f32x4 v;
            v[0] = acc[im][0][i]; v[1] = acc[im][1][i];
            v[2] = acc[im][2][i]; v[3] = acc[im][3][i];
            __builtin_nontemporal_store(v, (f32x4*)&out[m * NOUT + wave * 64 + l15 * 4]);
        }
    }
}

extern "C" void kernel_launch(void* const* d_in, const int* in_sizes, int n_in,
                              void* d_out, int out_size, void* d_ws, size_t ws_size,
                              hipStream_t stream) {
    const float* x = (const float*)d_in[0];
    const float* w = (const float*)d_in[1];
    const int* mi = (const int*)d_in[2];
    float* out = (float*)d_out;

    unsigned short* wb = (unsigned short*)d_ws;                      // 256 KB
    unsigned* hcode2 = (unsigned*)((char*)d_ws + NOUT * KP * 2);     // 1 KB

    prep_kernel<<<(NOUT * KP + 255) / 256, 256, 0, stream>>>(w, mi, wb, hcode2);
    pce_kernel<<<NSAMP / BM, 256, 0, stream>>>(x, wb, hcode2, out);
}

// Round 6
// 213.256 us; speedup vs baseline: 1.0281x; 1.0281x over previous
//
#include <hip/hip_runtime.h>

#define NSAMP 131072
#define DIMS 8
#define NPCE 495
#define KP 512          // K padded to 512
#define NOUT 256
#define BM 64           // samples per block
#define SK 32           // K per substage
#define NSTG (KP / SK)  // 16 substages
#define NCH 4           // K-chunks (128 K each = 4 substages)
#define NH 70           // half-products per 4-dim half (order<=4)
#define HS 68           // At/Bt sample stride: 136B, words==2 mod 32 -> banks spread by h
#define PS 40           // Psi row stride: 80B rows -> 16B-aligned b128 reads, uniform banks

typedef _Float16 half8 __attribute__((ext_vector_type(8)));
typedef _Float16 h16x2 __attribute__((ext_vector_type(2)));
typedef float f32x4 __attribute__((ext_vector_type(4)));

__device__ __forceinline__ unsigned short f2h(float f) {
    return __builtin_bit_cast(unsigned short, (_Float16)f);  // v_cvt_f16_f32, RTNE
}

// packed f16 multiply of two sample-pairs: one v_pk_mul_f16
__device__ __forceinline__ unsigned pkmul(unsigned a, unsigned b) {
    h16x2 r = __builtin_bit_cast(h16x2, a) * __builtin_bit_cast(h16x2, b);
    return __builtin_bit_cast(unsigned, r);
}

// Rank of 4-dim multi-index (sum<=4) in the canonical nest enumeration.
__device__ int rank4(int a0, int a1, int a2, int a3) {
    int idx = 0;
    for (int b0 = 0; b0 <= 4; ++b0)
        for (int b1 = 0; b1 <= 4 - b0; ++b1)
            for (int b2 = 0; b2 <= 4 - b0 - b1; ++b2)
                for (int b3 = 0; b3 <= 4 - b0 - b1 - b2; ++b3) {
                    if (b0 == a0 && b1 == a1 && b2 == a2 && b3 == a3) return idx;
                    ++idx;
                }
    return 0;
}

__device__ __forceinline__ int code_of(const int* mi, int k) {
    if (k >= NPCE) return 0;  // h1=h2=0 -> psi=1, weight row is zeroed
    const int* m = &mi[k * DIMS];
    int h1 = rank4(m[0], m[1], m[2], m[3]);
    int h2 = rank4(m[4], m[5], m[6], m[7]);
    return h1 | (h2 << 8);
}

// prep: weight -> f16 [256][512] with PERMUTED rows (epilogue dwordx4 stores):
// row n holds original column o = (n&~63) | ((n&15)<<2) | ((n>>4)&3).
// codes -> dword layout hcode2[kg][stage] = code(k0) | code(k0+1)<<16,
// k0 = stage*SK + kg*2  (per-thread-contiguous, uint4 per chunk in pce).
__global__ __launch_bounds__(256) void prep_kernel(const float* __restrict__ w,
                                                   const int* __restrict__ mi,
                                                   unsigned short* __restrict__ wb,
                                                   unsigned* __restrict__ hcode2) {
    int t = blockIdx.x * 256 + threadIdx.x;
    if (t < NOUT * KP) {
        int n = t >> 9;
        int k = t & (KP - 1);
        int o = (n & ~63) | ((n & 15) << 2) | ((n >> 4) & 3);
        float v = (k < NPCE) ? w[o * NPCE + k] : 0.0f;
        wb[t] = f2h(v);
    }
    if (t < 16 * NSTG) {
        int kg = t >> 4;        // 0..15
        int s = t & (NSTG - 1); // 0..15
        int k0 = s * SK + kg * 2;
        unsigned c0 = (unsigned)code_of(mi, k0);
        unsigned c1 = (unsigned)code_of(mi, k0 + 1);
        hcode2[kg * NSTG + s] = c0 | (c1 << 16);
    }
}

// Build 35 of the 70 half-products (compile-time range -> full DCE/CSE).
template <int LO, int HI>
__device__ __forceinline__ void build_half(const float H0[5], const float H1[5],
                                           const float H2[5], const float H3[5],
                                           unsigned short* dst, int s) {
    int idx = 0;
    #pragma unroll
    for (int a0 = 0; a0 <= 4; ++a0)
        #pragma unroll
        for (int a1 = 0; a1 <= 4 - a0; ++a1)
            #pragma unroll
            for (int a2 = 0; a2 <= 4 - a0 - a1; ++a2)
                #pragma unroll
                for (int a3 = 0; a3 <= 4 - a0 - a1 - a2; ++a3) {
                    if (idx >= LO && idx < HI) {
                        float p = H0[a0] * H1[a1] * H2[a2] * H3[a3];
                        dst[idx * HS + s] = f2h(p);
                    }
                    ++idx;
                }
}

__device__ __forceinline__ void hermite5(float x, float H[5]) {
    const float rn2 = 0.70710678118654752f;
    const float rn3 = 0.40824829046386302f;
    const float rn4 = 0.20412414523193151f;
    float r1 = x;
    float r2 = x * r1 - 1.0f;
    float r3 = x * r2 - 2.0f * r1;
    float r4 = x * r3 - 3.0f * r2;
    H[0] = 1.0f; H[1] = r1; H[2] = r2 * rn2; H[3] = r3 * rn3; H[4] = r4 * rn4;
}

__global__ __launch_bounds__(256, 4) void pce_kernel(const float* __restrict__ x,
                                                     const unsigned short* __restrict__ wb,
                                                     const unsigned* __restrict__ hcode2,
                                                     float* __restrict__ out) {
    __shared__ __attribute__((aligned(16))) unsigned short At[NH * HS];       // 9.52 KB
    __shared__ __attribute__((aligned(16))) unsigned short Bt[NH * HS];       // 9.52 KB
    __shared__ __attribute__((aligned(16))) unsigned short Psi[NCH][BM * PS]; // 20.48 KB
    // total 39.5 KB -> 4 blocks/CU

    const int tid = threadIdx.x;
    const int lane = tid & 63;
    const int wave = tid >> 6;
    const int quad = lane >> 4;
    const int l15 = lane & 15;
    const int m0 = blockIdx.x * BM;

    // Gather mapping: thread owns 2 k (pair kg) x 4 samples (s0..s0+3).
    const int kg = tid & 15;
    const int s0 = (tid >> 4) * 4;
    const unsigned* hcp = &hcode2[kg * NSTG];

    // ---- issue early prefetches (hidden under the builder) ----
    uint4 cdc = *(const uint4*)&hcp[0];   // chunk-0 codes (4 substages)

    // 2-deep W prefetch: bn[parity] holds substage s columns -> 2 substages of
    // latency cover for the L2 reads.
    half8 bn[2][4];
    auto loadB = [&](int s, half8* dst) {
        #pragma unroll
        for (int in = 0; in < 4; ++in) {
            int n = wave * 64 + in * 16 + l15;
            dst[in] = *(const half8*)&wb[n * KP + s * SK + quad * 8];
        }
    };
    loadB(0, bn[0]);
    loadB(1, bn[1]);

    // ---- Builder: wave -> (half = wave>>1, term range = wave&1), lane = sample.
    {
        const int half = wave >> 1;
        const float4 xv = *(const float4*)&x[(m0 + lane) * DIMS + half * 4];
        float H0[5], H1[5], H2[5], H3[5];
        hermite5(xv.x, H0);
        hermite5(xv.y, H1);
        hermite5(xv.z, H2);
        hermite5(xv.w, H3);
        unsigned short* dst = half ? Bt : At;
        if (wave & 1) build_half<35, 70>(H0, H1, H2, H3, dst, lane);
        else          build_half<0, 35>(H0, H1, H2, H3, dst, lane);
    }

    f32x4 acc[4][4] = {};

    // Produce one 32-wide substage into Psi[buf]:
    // 4 ds_read_b64 + 4 v_pk_mul_f16 + 4 v_perm_b32 + 4 ds_write_b32.
    auto gather = [&](unsigned c, int buf) {
        int h1a = c & 255, h2a = (c >> 8) & 255;   // even k
        int h1b = (c >> 16) & 255, h2b = c >> 24;  // odd k
        uint2 av0 = *(const uint2*)&At[h1a * HS + s0];
        uint2 bv0 = *(const uint2*)&Bt[h2a * HS + s0];
        uint2 av1 = *(const uint2*)&At[h1b * HS + s0];
        uint2 bv1 = *(const uint2*)&Bt[h2b * HS + s0];
        unsigned p0l = pkmul(av0.x, bv0.x), p0h = pkmul(av0.y, bv0.y);
        unsigned p1l = pkmul(av1.x, bv1.x), p1h = pkmul(av1.y, bv1.y);
        unsigned short* base = &Psi[buf][kg * 2];
        *(unsigned*)&base[(s0 + 0) * PS] = __builtin_amdgcn_perm(p1l, p0l, 0x05040100u);
        *(unsigned*)&base[(s0 + 1) * PS] = __builtin_amdgcn_perm(p1l, p0l, 0x07060302u);
        *(unsigned*)&base[(s0 + 2) * PS] = __builtin_amdgcn_perm(p1h, p0h, 0x05040100u);
        *(unsigned*)&base[(s0 + 3) * PS] = __builtin_amdgcn_perm(p1h, p0h, 0x07060302u);
    };

    __syncthreads();   // At/Bt ready

    uint4 cdn = cdc;
    for (int c = 0; c < NCH; ++c) {
        // ---- produce phase: 4 substages, no intervening syncs ----
        if (c > 0) __syncthreads();   // consume of chunk c-1 fully drained
        gather(cdc.x, 0);
        gather(cdc.y, 1);
        gather(cdc.z, 2);
        gather(cdc.w, 3);
        __syncthreads();              // Psi chunk visible
        if (c + 1 < NCH) cdn = *(const uint4*)&hcp[(c + 1) * 4];

        // ---- consume phase: 4 substages x 16 MFMA, barrier-free stream ----
        #pragma unroll
        for (int t = 0; t < 4; ++t) {
            const int s = c * 4 + t;
            half8 bc[4];
            #pragma unroll
            for (int in = 0; in < 4; ++in) bc[in] = bn[s & 1][in];  // capture (vmcnt)
            if (s + 2 < NSTG) loadB(s + 2, bn[s & 1]);              // refill slot
            half8 af[4];
            #pragma unroll
            for (int im = 0; im < 4; ++im)
                af[im] = *(const half8*)&Psi[t][(im * 16 + l15) * PS + quad * 8];
            #pragma unroll
            for (int im = 0; im < 4; ++im)
                #pragma unroll
                for (int in = 0; in < 4; ++in)
                    acc[im][in] = __builtin_amdgcn_mfma_f32_16x16x32_f16(
                        af[im], bc[in], acc[im][in], 0, 0, 0);
        }
        cdc = cdn;
    }

    // ---- epilogue: permuted weights make lane's 4 'in' values 4 consecutive
    // output columns -> coalesced dwordx4 stores (16 per thread). Plain stores:
    // they write-combine in L2 (R5 showed nontemporal inflates HBM WRITE_SIZE
    // 143->172 MB and costs 13% time on this BW-rationed kernel).
    #pragma unroll
    for (int im = 0; im < 4; ++im) {
        #pragma unroll
        for (int i = 0; i < 4; ++i) {
            int m = m0 + im * 16 + quad * 4 + i;
            float4 v = make_float4(acc[im][0][i], acc[im][1][i],
                                   acc[im][2][i], acc[im][3][i]);
            *(float4*)&out[m * NOUT + wave * 64 + l15 * 4] = v;
        }
    }
}

extern "C" void kernel_launch(void* const* d_in, const int* in_sizes, int n_in,
                              void* d_out, int out_size, void* d_ws, size_t ws_size,
                              hipStream_t stream) {
    const float* x = (const float*)d_in[0];
    const float* w = (const float*)d_in[1];
    const int* mi = (const int*)d_in[2];
    float* out = (float*)d_out;

    unsigned short* wb = (unsigned short*)d_ws;                      // 256 KB
    unsigned* hcode2 = (unsigned*)((char*)d_ws + NOUT * KP * 2);     // 1 KB

    prep_kernel<<<(NOUT * KP + 255) / 256, 256, 0, stream>>>(w, mi, wb, hcode2);
    pce_kernel<<<NSAMP / BM, 256, 0, stream>>>(x, wb, hcode2, out);
}

// Round 7
// 200.755 us; speedup vs baseline: 1.0921x; 1.0623x over previous
//
#include <hip/hip_runtime.h>

#define NSAMP 131072
#define DIMS 8
#define NPCE 495
#define KP 512          // K padded to 512
#define NOUT 256
#define BM 64           // samples per block
#define SK 32           // K per substage
#define NSTG (KP / SK)  // 16 substages
#define NCH 4           // K-chunks (128 K each = 4 substages)
#define NH 70           // half-products per 4-dim half (order<=4)
#define HS 68           // At/Bt sample stride: 136B, words==2 mod 32 -> banks spread by h
#define PS 40           // Psi row stride: 80B rows -> 16B-aligned b128 reads, uniform banks

typedef _Float16 half8 __attribute__((ext_vector_type(8)));
typedef _Float16 h16x2 __attribute__((ext_vector_type(2)));
typedef float f32x4 __attribute__((ext_vector_type(4)));

__device__ __forceinline__ unsigned short f2h(float f) {
    return __builtin_bit_cast(unsigned short, (_Float16)f);  // v_cvt_f16_f32, RTNE
}

// packed f16 multiply of two sample-pairs: one v_pk_mul_f16
__device__ __forceinline__ unsigned pkmul(unsigned a, unsigned b) {
    h16x2 r = __builtin_bit_cast(h16x2, a) * __builtin_bit_cast(h16x2, b);
    return __builtin_bit_cast(unsigned, r);
}

// Rank of 4-dim multi-index (sum<=4) in the canonical nest enumeration.
__device__ int rank4(int a0, int a1, int a2, int a3) {
    int idx = 0;
    for (int b0 = 0; b0 <= 4; ++b0)
        for (int b1 = 0; b1 <= 4 - b0; ++b1)
            for (int b2 = 0; b2 <= 4 - b0 - b1; ++b2)
                for (int b3 = 0; b3 <= 4 - b0 - b1 - b2; ++b3) {
                    if (b0 == a0 && b1 == a1 && b2 == a2 && b3 == a3) return idx;
                    ++idx;
                }
    return 0;
}

__device__ __forceinline__ int code_of(const int* mi, int k) {
    if (k >= NPCE) return 0;  // h1=h2=0 -> psi=1, weight row is zeroed
    const int* m = &mi[k * DIMS];
    int h1 = rank4(m[0], m[1], m[2], m[3]);
    int h2 = rank4(m[4], m[5], m[6], m[7]);
    return h1 | (h2 << 8);
}

// prep: weight -> f16 [256][512] with PERMUTED rows (epilogue dwordx4 stores):
// row n holds original column o = (n&~63) | ((n&15)<<2) | ((n>>4)&3).
// codes -> dword layout hcode2[kg][stage] = code(k0) | code(k0+1)<<16,
// k0 = stage*SK + kg*2  (per-thread-contiguous, uint4 per chunk in pce).
__global__ __launch_bounds__(256) void prep_kernel(const float* __restrict__ w,
                                                   const int* __restrict__ mi,
                                                   unsigned short* __restrict__ wb,
                                                   unsigned* __restrict__ hcode2) {
    int t = blockIdx.x * 256 + threadIdx.x;
    if (t < NOUT * KP) {
        int n = t >> 9;
        int k = t & (KP - 1);
        int o = (n & ~63) | ((n & 15) << 2) | ((n >> 4) & 3);
        float v = (k < NPCE) ? w[o * NPCE + k] : 0.0f;
        wb[t] = f2h(v);
    }
    if (t < 16 * NSTG) {
        int kg = t >> 4;        // 0..15
        int s = t & (NSTG - 1); // 0..15
        int k0 = s * SK + kg * 2;
        unsigned c0 = (unsigned)code_of(mi, k0);
        unsigned c1 = (unsigned)code_of(mi, k0 + 1);
        hcode2[kg * NSTG + s] = c0 | (c1 << 16);
    }
}

// Build 35 of the 70 half-products (compile-time range -> full DCE/CSE).
template <int LO, int HI>
__device__ __forceinline__ void build_half(const float H0[5], const float H1[5],
                                           const float H2[5], const float H3[5],
                                           unsigned short* dst, int s) {
    int idx = 0;
    #pragma unroll
    for (int a0 = 0; a0 <= 4; ++a0)
        #pragma unroll
        for (int a1 = 0; a1 <= 4 - a0; ++a1)
            #pragma unroll
            for (int a2 = 0; a2 <= 4 - a0 - a1; ++a2)
                #pragma unroll
                for (int a3 = 0; a3 <= 4 - a0 - a1 - a2; ++a3) {
                    if (idx >= LO && idx < HI) {
                        float p = H0[a0] * H1[a1] * H2[a2] * H3[a3];
                        dst[idx * HS + s] = f2h(p);
                    }
                    ++idx;
                }
}

__device__ __forceinline__ void hermite5(float x, float H[5]) {
    const float rn2 = 0.70710678118654752f;
    const float rn3 = 0.40824829046386302f;
    const float rn4 = 0.20412414523193151f;
    float r1 = x;
    float r2 = x * r1 - 1.0f;
    float r3 = x * r2 - 2.0f * r1;
    float r4 = x * r3 - 3.0f * r2;
    H[0] = 1.0f; H[1] = r1; H[2] = r2 * rn2; H[3] = r3 * rn3; H[4] = r4 * rn4;
}

__global__ __launch_bounds__(256, 4) void pce_kernel(const float* __restrict__ x,
                                                     const unsigned short* __restrict__ wb,
                                                     const unsigned* __restrict__ hcode2,
                                                     float* __restrict__ out) {
    __shared__ __attribute__((aligned(16))) unsigned short At[NH * HS];       // 9.52 KB
    __shared__ __attribute__((aligned(16))) unsigned short Bt[NH * HS];       // 9.52 KB
    __shared__ __attribute__((aligned(16))) unsigned short Psi[NCH][BM * PS]; // 20.48 KB
    // total 39.5 KB -> 4 blocks/CU

    const int tid = threadIdx.x;
    const int lane = tid & 63;
    const int wave = tid >> 6;
    const int quad = lane >> 4;
    const int l15 = lane & 15;
    const int m0 = blockIdx.x * BM;

    // Gather mapping: thread owns 2 k (pair kg) x 4 samples (s0..s0+3).
    const int kg = tid & 15;
    const int s0 = (tid >> 4) * 4;
    const unsigned* hcp = &hcode2[kg * NSTG];

    // ---- issue early prefetches (hidden under the builder) ----
    uint4 cdc = *(const uint4*)&hcp[0];   // chunk-0 codes (4 substages)

    half8 bn[4];
    auto loadB = [&](int s, half8* dst) {
        #pragma unroll
        for (int in = 0; in < 4; ++in) {
            int n = wave * 64 + in * 16 + l15;
            dst[in] = *(const half8*)&wb[n * KP + s * SK + quad * 8];
        }
    };
    loadB(0, bn);

    // ---- Builder: wave -> (half = wave>>1, term range = wave&1), lane = sample.
    {
        const int half = wave >> 1;
        const float4 xv = *(const float4*)&x[(m0 + lane) * DIMS + half * 4];
        float H0[5], H1[5], H2[5], H3[5];
        hermite5(xv.x, H0);
        hermite5(xv.y, H1);
        hermite5(xv.z, H2);
        hermite5(xv.w, H3);
        unsigned short* dst = half ? Bt : At;
        if (wave & 1) build_half<35, 70>(H0, H1, H2, H3, dst, lane);
        else          build_half<0, 35>(H0, H1, H2, H3, dst, lane);
    }

    f32x4 acc[4][4] = {};

    // Produce one 32-wide substage into Psi[buf]:
    // 4 ds_read_b64 + 4 v_pk_mul_f16 + 4 v_perm_b32 + 4 ds_write_b32.
    auto gather = [&](unsigned c, int buf) {
        int h1a = c & 255, h2a = (c >> 8) & 255;   // even k
        int h1b = (c >> 16) & 255, h2b = c >> 24;  // odd k
        uint2 av0 = *(const uint2*)&At[h1a * HS + s0];
        uint2 bv0 = *(const uint2*)&Bt[h2a * HS + s0];
        uint2 av1 = *(const uint2*)&At[h1b * HS + s0];
        uint2 bv1 = *(const uint2*)&Bt[h2b * HS + s0];
        unsigned p0l = pkmul(av0.x, bv0.x), p0h = pkmul(av0.y, bv0.y);
        unsigned p1l = pkmul(av1.x, bv1.x), p1h = pkmul(av1.y, bv1.y);
        unsigned short* base = &Psi[buf][kg * 2];
        *(unsigned*)&base[(s0 + 0) * PS] = __builtin_amdgcn_perm(p1l, p0l, 0x05040100u);
        *(unsigned*)&base[(s0 + 1) * PS] = __builtin_amdgcn_perm(p1l, p0l, 0x07060302u);
        *(unsigned*)&base[(s0 + 2) * PS] = __builtin_amdgcn_perm(p1h, p0h, 0x05040100u);
        *(unsigned*)&base[(s0 + 3) * PS] = __builtin_amdgcn_perm(p1h, p0h, 0x07060302u);
    };

    __syncthreads();   // At/Bt ready

    uint4 cdn = cdc;
    for (int c = 0; c < NCH; ++c) {
        // ---- produce phase: 4 substages, no intervening syncs ----
        if (c > 0) __syncthreads();   // consume of chunk c-1 fully drained
        gather(cdc.x, 0);
        gather(cdc.y, 1);
        gather(cdc.z, 2);
        gather(cdc.w, 3);
        __syncthreads();              // Psi chunk visible
        if (c + 1 < NCH) cdn = *(const uint4*)&hcp[(c + 1) * 4];

        // ---- consume phase: 4 substages x 16 MFMA, barrier-free stream ----
        #pragma unroll
        for (int t = 0; t < 4; ++t) {
            const int s = c * 4 + t;
            half8 bc[4];
            #pragma unroll
            for (int in = 0; in < 4; ++in) bc[in] = bn[in];  // capture prefetched W
            if (s + 1 < NSTG) loadB(s + 1, bn);              // global, hidden by MFMA
            half8 af[4];
            #pragma unroll
            for (int im = 0; im < 4; ++im)
                af[im] = *(const half8*)&Psi[t][(im * 16 + l15) * PS + quad * 8];
            #pragma unroll
            for (int im = 0; im < 4; ++im)
                #pragma unroll
                for (int in = 0; in < 4; ++in)
                    acc[im][in] = __builtin_amdgcn_mfma_f32_16x16x32_f16(
                        af[im], bc[in], acc[im][in], 0, 0, 0);
        }
        cdc = cdn;
    }

    // ---- epilogue: permuted weights make lane's 4 'in' values 4 consecutive
    // output columns -> coalesced dwordx4 stores (16 per thread).
    #pragma unroll
    for (int im = 0; im < 4; ++im) {
        #pragma unroll
        for (int i = 0; i < 4; ++i) {
            int m = m0 + im * 16 + quad * 4 + i;
            float4 v = make_float4(acc[im][0][i], acc[im][1][i],
                                   acc[im][2][i], acc[im][3][i]);
            *(float4*)&out[m * NOUT + wave * 64 + l15 * 4] = v;
        }
    }
}

extern "C" void kernel_launch(void* const* d_in, const int* in_sizes, int n_in,
                              void* d_out, int out_size, void* d_ws, size_t ws_size,
                              hipStream_t stream) {
    const float* x = (const float*)d_in[0];
    const float* w = (const float*)d_in[1];
    const int* mi = (const int*)d_in[2];
    float* out = (float*)d_out;

    unsigned short* wb = (unsigned short*)d_ws;                      // 256 KB
    unsigned* hcode2 = (unsigned*)((char*)d_ws + NOUT * KP * 2);     // 1 KB

    prep_kernel<<<(NOUT * KP + 255) / 256, 256, 0, stream>>>(w, mi, wb, hcode2);
    pce_kernel<<<NSAMP / BM, 256, 0, stream>>>(x, wb, hcode2, out);
}